// Round 2
// baseline (608.711 us; speedup 1.0000x reference)
//
#include <hip/hip_runtime.h>
#include <hip/hip_bf16.h>

typedef __bf16 bf16;
typedef __bf16 bf16x4 __attribute__((ext_vector_type(4)));
typedef __bf16 bf16x8 __attribute__((ext_vector_type(8)));
typedef float floatx4 __attribute__((ext_vector_type(4)));

#define MFMA16(a, b, c) __builtin_amdgcn_mfma_f32_16x16x32_bf16((a), (b), (c), 0, 0, 0)

// ---- workspace layout (bytes) ----
static constexpr long OFF_QKV   = 0;            // bf16 [65536][1536]  201326592
static constexpr long OFF_XB    = 201326592;    // bf16 [65536][512]   67108864 (x_bf16, later attn_out)
static constexpr long OFF_WQKV  = 268435456;    // bf16 [1536][512]    1572864
static constexpr long OFF_WPROJ = 270008320;    // bf16 [512][512]     524288
static constexpr long OFF_BT    = 270532608;    // f32  [225][16]      (padded to 16384)
static constexpr long OFF_RB    = 270548992;    // f32  [16][64][64]   262144
// total ~258.3 MB

__device__ __forceinline__ void load_lds16(const bf16* g, bf16* l) {
  // async global->LDS, 16B per lane; LDS dest is wave-uniform base + lane*16
  __builtin_amdgcn_global_load_lds((const __attribute__((address_space(1))) void*)(g),
                                   (__attribute__((address_space(3))) void*)(l), 16, 0, 0);
}

// ---------------- fp32 -> bf16 convert (8 elems/thread) ----------------
__global__ __launch_bounds__(256) void cvt_f32_bf16(const float* __restrict__ src,
                                                    bf16* __restrict__ dst, int n8) {
  int i = blockIdx.x * 256 + threadIdx.x;
  if (i < n8) {
    const float4* s = (const float4*)src;
    float4 a = s[2 * i], b = s[2 * i + 1];
    bf16x8 o;
    o[0] = (bf16)a.x; o[1] = (bf16)a.y; o[2] = (bf16)a.z; o[3] = (bf16)a.w;
    o[4] = (bf16)b.x; o[5] = (bf16)b.y; o[6] = (bf16)b.z; o[7] = (bf16)b.w;
    ((bf16x8*)dst)[i] = o;
  }
}

// ---------------- CPB-MLP: bias_table[225][16] ----------------
__global__ __launch_bounds__(256) void cpb_mlp(const float* __restrict__ table,
                                               const float* __restrict__ w1,
                                               const float* __restrict__ b1,
                                               const float* __restrict__ w2,
                                               float* __restrict__ bias_table) {
  __shared__ float hid[512];
  const int e = blockIdx.x;                   // 0..224
  const float t0 = table[e * 2 + 0], t1 = table[e * 2 + 1];
  for (int j = threadIdx.x; j < 512; j += 256) {
    float hv = t0 * w1[j * 2 + 0] + t1 * w1[j * 2 + 1] + b1[j];
    hid[j] = hv > 0.f ? hv : 0.f;
  }
  __syncthreads();
  const int hd = threadIdx.x >> 4, l = threadIdx.x & 15;
  float p = 0.f;
  for (int j = l; j < 512; j += 16) p += hid[j] * w2[hd * 512 + j];
  #pragma unroll
  for (int d = 8; d >= 1; d >>= 1) p += __shfl_xor(p, d, 16);
  if (l == 0) bias_table[e * 16 + hd] = p;
}

// ---------------- gather + sigmoid: rel_bias[16][64][64] ----------------
__global__ __launch_bounds__(256) void cpb_gather(const float* __restrict__ bias_table,
                                                  const int* __restrict__ idx,
                                                  float* __restrict__ rel_bias) {
  int f = blockIdx.x * 256 + threadIdx.x;     // 65536 total
  int h = f >> 12, ij = f & 4095;
  float v = bias_table[idx[ij] * 16 + h];
  rel_bias[f] = 16.f / (1.f + __expf(-v));
}

// ---------------- bf16 GEMM: C[M,NN] = A[M,512] @ Bt[NN,512]^T (+bias) ----------------
// R2: 256x128 tile, BK=64, 8 waves (512 thr), RING-3 LDS (144KB, 1 block/CU) with
// COUNTED vmcnt (T3+T4): iteration t issues stage(t+2) into buf (t+2)%3 (= buf of the
// already-consumed tile t-1), computes tile t, then s_waitcnt vmcnt(6) — tile t+1's 6
// loads proven landed, tile t+2's 6 stay IN FLIGHT across the raw s_barrier. vmcnt never
// drains to 0 in steady state (the __syncthreads() vmcnt(0) drain was the R0/R1 stall:
// MfmaUtil 23%, 58% idle). Lookahead = 2 K-tiles (~2500 MFMA-issue cyc) >> ~900cyc HBM.
// T5 setprio around each MFMA cluster. XOR-swizzled LDS (0 bank conflicts measured).
// Epilogue: swapped-operand C layout -> 8B/16B vector stores (kept from R1: WRITE -12MB).
template <int NN, bool QKV>
__global__ __launch_bounds__(512, 2) void gemm_bt(const bf16* __restrict__ A,
                                                  const bf16* __restrict__ Bt,
                                                  void* __restrict__ outv,
                                                  const float* __restrict__ bias_a,
                                                  const float* __restrict__ bias_b) {
  constexpr int K = 512;
  constexpr int KT = K / 64;          // 8 K-tiles
  constexpr int nblk = NN / 128;
  __shared__ alignas(16) bf16 As[3][256 * 64];   // 96 KB
  __shared__ alignas(16) bf16 Bs[3][128 * 64];   // 48 KB
  const int tid = threadIdx.x;
  const int lane = tid & 63;
  const int wv = tid >> 6;                // 0..7
  // XCD swizzle: bid%8 = XCD; 32 m-blocks per XCD, n advances outer -> B-panel (128KB)
  // L2-resident per XCD, A-slab reuse within XCD across n-rounds.
  const int bid = blockIdx.x;
  const int xcd = bid & 7;
  const int g = bid >> 3;                 // 0 .. 32*nblk-1
  const int mb = xcd * 32 + (g & 31);     // 256 m-blocks, 32 per XCD
  const int nb = g >> 5;
  const long m0 = (long)mb * 256;
  const int n0 = nb * 128;
  const int wm = (wv & 3) * 64;           // 4 M-waves
  const int wn = (wv >> 2) * 64;          // 2 N-waves
  const int cl = lane & 15;
  const int cq = lane >> 4;

  const floatx4 fzero = {0.f, 0.f, 0.f, 0.f};
  floatx4 acc[4][4];
  #pragma unroll
  for (int i = 0; i < 4; ++i)
    #pragma unroll
    for (int j = 0; j < 4; ++j) acc[i][j] = fzero;

  // staging slot -> (row, swizzled 8-elem group); A uses r=0..3 (256 rows), B r=0..1
  int srow[4], sc8[4];
  #pragma unroll
  for (int r = 0; r < 4; ++r) {
    int s = r * 512 + tid;
    srow[r] = s >> 3;
    sc8[r] = (s & 7) ^ (srow[r] & 7);
  }
  const int wbase = tid & ~63;  // wave-uniform slot base

  auto stage = [&](int buf, int kt) {
    const int k0 = kt * 64;
    #pragma unroll
    for (int r = 0; r < 4; ++r) {
      const bf16* ga = A + (m0 + srow[r]) * (long)K + (k0 + sc8[r] * 8);
      load_lds16(ga, &As[buf][(r * 512 + wbase) * 8]);
    }
    #pragma unroll
    for (int r = 0; r < 2; ++r) {
      const bf16* gb = Bt + (long)(n0 + srow[r]) * K + (k0 + sc8[r] * 8);
      load_lds16(gb, &Bs[buf][(r * 512 + wbase) * 8]);
    }
  };

  auto compute = [&](int buf) {
    #pragma unroll
    for (int kk = 0; kk < 2; ++kk) {
      bf16x8 af[4], bfr[4];
      const int gg = kk * 4 + cq;
      #pragma unroll
      for (int t = 0; t < 4; ++t) {
        const int mr = wm + t * 16 + cl;
        af[t] = *(const bf16x8*)&As[buf][(mr * 8 + (gg ^ (mr & 7))) * 8];
        const int nr = wn + t * 16 + cl;
        bfr[t] = *(const bf16x8*)&Bs[buf][(nr * 8 + (gg ^ (nr & 7))) * 8];
      }
      __builtin_amdgcn_s_setprio(1);
      #pragma unroll
      for (int i = 0; i < 4; ++i)
        #pragma unroll
        for (int j = 0; j < 4; ++j)
          acc[i][j] = MFMA16(bfr[j], af[i], acc[i][j]);  // swapped: col-vector C layout
      __builtin_amdgcn_s_setprio(0);
    }
  };

  // prologue: 2 K-tiles in flight; wait only for tile0 (6 newest = tile1 stay in flight)
  stage(0, 0);
  stage(1, 1);
  asm volatile("s_waitcnt vmcnt(6)" ::: "memory");
  __builtin_amdgcn_s_barrier();

  #pragma unroll
  for (int kt = 0; kt < KT; ++kt) {
    if (kt + 2 < KT) stage((kt + 2) % 3, kt + 2);   // writes buf of dead tile kt-1
    __builtin_amdgcn_sched_barrier(0);              // keep load-issue ahead of compute
    compute(kt % 3);
    __builtin_amdgcn_sched_barrier(0);              // pin MFMA cluster inside the phase
    if (kt + 2 < KT)
      asm volatile("s_waitcnt vmcnt(6)" ::: "memory");   // tile kt+1 landed; kt+2 in flight
    else if (kt + 1 < KT)
      asm volatile("s_waitcnt vmcnt(0)" ::: "memory");   // last prefetched tile
    if (kt + 1 < KT) __builtin_amdgcn_s_barrier();
  }

  // epilogue: lane holds C[m0+wm+i*16+cl][n0+wn+j*16+cq*4 + r], r=0..3 consecutive cols
  const int cq4 = cq * 4;
  #pragma unroll
  for (int i = 0; i < 4; ++i) {
    const long m = m0 + wm + i * 16 + cl;
    #pragma unroll
    for (int j = 0; j < 4; ++j) {
      const int nbase = n0 + wn + j * 16 + cq4;
      if constexpr (QKV) {
        // qkv bias: [q_bias | zeros | v_bias]; 4-col group never straddles a boundary
        float4 bb = {0.f, 0.f, 0.f, 0.f};
        if (nbase < 512) bb = *(const float4*)&bias_a[nbase];
        else if (nbase >= 1024) bb = *(const float4*)&bias_b[nbase - 1024];
        bf16x4 o;
        o[0] = (bf16)(acc[i][j][0] + bb.x);
        o[1] = (bf16)(acc[i][j][1] + bb.y);
        o[2] = (bf16)(acc[i][j][2] + bb.z);
        o[3] = (bf16)(acc[i][j][3] + bb.w);
        *(bf16x4*)((bf16*)outv + m * NN + nbase) = o;
      } else {
        const float4 bb = *(const float4*)&bias_a[nbase];
        float4 o;
        o.x = acc[i][j][0] + bb.x;
        o.y = acc[i][j][1] + bb.y;
        o.z = acc[i][j][2] + bb.z;
        o.w = acc[i][j][3] + bb.w;
        *(float4*)((float*)outv + m * NN + nbase) = o;
      }
    }
  }
}

// ---------------- fused window attention: one block per (window, head) ----------------
// Head-pair XCD swizzle: (b,2j) and (b,2j+1) share 128B qkv cachelines; keep them on
// the same XCD, adjacent in dispatch order, so the second block hits L2.
// LDS pool 24.5KB (P aliases qh/ql after a barrier) -> 5-6 blocks/CU by LDS.
__global__ __launch_bounds__(256, 5) void attn_kernel(const bf16* __restrict__ qkv,
                                                      const float* __restrict__ mask,
                                                      const float* __restrict__ lscale,
                                                      const float* __restrict__ rel_bias,
                                                      bf16* __restrict__ out) {
  const int bid = blockIdx.x;
  const int xcd = bid & 7;
  const int t = bid >> 3;                  // 0..2047
  const int p = xcd + ((t >> 1) << 3);     // pair index 0..8191
  const int b = p >> 3;                    // window 0..1023
  const int h = ((p & 7) << 1) | (t & 1);  // head 0..15
  const int wi = b & 63;
  const int tid = threadIdx.x;
  const int lane = tid & 63;
  const int wv = tid >> 6;
  const int cl = lane & 15;
  const int cq = lane >> 4;

  // single pool: qh/ql/kh/kl [64x40] each, vT [32x72]; ps [64x72] aliases qh+ql
  __shared__ alignas(16) bf16 smem[12544];  // 25088 B
  bf16* qh_s = smem;            // 2560 elems
  bf16* ql_s = smem + 2560;
  bf16* kh_s = smem + 5120;
  bf16* kl_s = smem + 7680;
  bf16* vT   = smem + 10240;    // 2304 elems
  bf16* ps   = smem;            // 4608 elems, reused after barrier

  {  // stage + l2-normalize q,k (fp32 norm, hi/lo bf16 split); transpose v
    const int r = tid >> 2, seg = tid & 3;
    const bf16* base = qkv + (long)(b * 64 + r) * 1536 + h * 32 + seg * 8;
    float f[8], ss;
    bf16x8 hi, lo;

    bf16x8 qv = *(const bf16x8*)(base);
    ss = 0.f;
    #pragma unroll
    for (int j = 0; j < 8; ++j) { f[j] = (float)qv[j]; ss += f[j] * f[j]; }
    ss += __shfl_xor(ss, 1, 4); ss += __shfl_xor(ss, 2, 4);
    float s1 = 1.f / fmaxf(sqrtf(ss), 1e-12f);
    #pragma unroll
    for (int j = 0; j < 8; ++j) {
      float xn = f[j] * s1;
      bf16 xh = (bf16)xn;
      hi[j] = xh; lo[j] = (bf16)(xn - (float)xh);
    }
    *(bf16x8*)&qh_s[r * 40 + seg * 8] = hi;
    *(bf16x8*)&ql_s[r * 40 + seg * 8] = lo;

    bf16x8 kv = *(const bf16x8*)(base + 512);
    ss = 0.f;
    #pragma unroll
    for (int j = 0; j < 8; ++j) { f[j] = (float)kv[j]; ss += f[j] * f[j]; }
    ss += __shfl_xor(ss, 1, 4); ss += __shfl_xor(ss, 2, 4);
    s1 = 1.f / fmaxf(sqrtf(ss), 1e-12f);
    #pragma unroll
    for (int j = 0; j < 8; ++j) {
      float xn = f[j] * s1;
      bf16 xh = (bf16)xn;
      hi[j] = xh; lo[j] = (bf16)(xn - (float)xh);
    }
    *(bf16x8*)&kh_s[r * 40 + seg * 8] = hi;
    *(bf16x8*)&kl_s[r * 40 + seg * 8] = lo;

    bf16x8 vv = *(const bf16x8*)(base + 1024);
    #pragma unroll
    for (int j = 0; j < 8; ++j) vT[(seg * 8 + j) * 72 + r] = vv[j];
  }
  __syncthreads();

  const float sc = __expf(fminf(lscale[h], 4.6051701859880914f));  // exp(min(ls, ln 100))

  // QK^T for this wave's 16-row m-tile; 3-MFMA split-bf16 for accuracy
  const int mrow = wv * 16 + cl;
  const bf16x8 aqh = *(const bf16x8*)&qh_s[mrow * 40 + cq * 8];
  const bf16x8 aql = *(const bf16x8*)&ql_s[mrow * 40 + cq * 8];
  floatx4 sacc[4];
  #pragma unroll
  for (int nt = 0; nt < 4; ++nt) {
    const int nr = nt * 16 + cl;
    const bf16x8 bkh = *(const bf16x8*)&kh_s[nr * 40 + cq * 8];
    const bf16x8 bkl = *(const bf16x8*)&kl_s[nr * 40 + cq * 8];
    floatx4 a = {0.f, 0.f, 0.f, 0.f};
    a = MFMA16(aql, bkh, a);
    a = MFMA16(aqh, bkl, a);
    a = MFMA16(aqh, bkh, a);
    sacc[nt] = a;
  }
  __syncthreads();  // all waves done reading qh/ql/kh/kl before ps overwrites them

  // scale + rel_bias + mask, fp32 softmax over 64 cols (16 lanes x 4 nt)
  float pw[4][4];  // [rg][nt]
  #pragma unroll
  for (int rg = 0; rg < 4; ++rg) {
    const int row = wv * 16 + cq * 4 + rg;
    const float* rbp = rel_bias + h * 4096 + row * 64;
    const float* mkp = mask + wi * 4096 + row * 64;
    float mxv = -1e30f;
    #pragma unroll
    for (int nt = 0; nt < 4; ++nt) {
      float s = sacc[nt][rg] * sc + rbp[nt * 16 + cl] + mkp[nt * 16 + cl];
      pw[rg][nt] = s;
      mxv = fmaxf(mxv, s);
    }
    #pragma unroll
    for (int d = 8; d >= 1; d >>= 1) mxv = fmaxf(mxv, __shfl_xor(mxv, d, 16));
    float sm = 0.f;
    #pragma unroll
    for (int nt = 0; nt < 4; ++nt) {
      float e = __expf(pw[rg][nt] - mxv);
      pw[rg][nt] = e;
      sm += e;
    }
    #pragma unroll
    for (int d = 8; d >= 1; d >>= 1) sm += __shfl_xor(sm, d, 16);
    const float inv = 1.f / sm;
    #pragma unroll
    for (int nt = 0; nt < 4; ++nt)
      ps[row * 72 + nt * 16 + cl] = (bf16)(pw[rg][nt] * inv);
  }
  // no barrier needed: each wave reads back only its own 16 P-rows (within-wave lgkmcnt)

  // PV: O[64x32] = P[64x64] @ V[64x32] via vT; operands SWAPPED so each lane holds
  // 4 consecutive head-dims of one row -> 2x bf16x4 stores instead of 8 scalar
  floatx4 oacc[2];
  oacc[0] = (floatx4){0.f, 0.f, 0.f, 0.f};
  oacc[1] = (floatx4){0.f, 0.f, 0.f, 0.f};
  #pragma unroll
  for (int ks = 0; ks < 2; ++ks) {
    const bf16x8 ap = *(const bf16x8*)&ps[(wv * 16 + cl) * 72 + ks * 32 + cq * 8];
    #pragma unroll
    for (int nt = 0; nt < 2; ++nt) {
      const bf16x8 bv = *(const bf16x8*)&vT[(nt * 16 + cl) * 72 + ks * 32 + cq * 8];
      oacc[nt] = MFMA16(bv, ap, oacc[nt]);  // swapped: O^T fragment
    }
  }
  // lane holds O[wv*16 + cl][nt*16 + cq*4 + r]
  const long obase = (long)(b * 64 + wv * 16 + cl) * 512 + h * 32 + cq * 4;
  #pragma unroll
  for (int nt = 0; nt < 2; ++nt) {
    bf16x4 o;
    #pragma unroll
    for (int r = 0; r < 4; ++r) o[r] = (bf16)oacc[nt][r];
    *(bf16x4*)&out[obase + nt * 16] = o;
  }
}

extern "C" void kernel_launch(void* const* d_in, const int* in_sizes, int n_in,
                              void* d_out, int out_size, void* d_ws, size_t ws_size,
                              hipStream_t stream) {
  const float* x      = (const float*)d_in[0];
  const float* mask   = (const float*)d_in[1];
  const float* qkv_w  = (const float*)d_in[2];
  const float* q_bias = (const float*)d_in[3];
  const float* v_bias = (const float*)d_in[4];
  const float* lsc    = (const float*)d_in[5];
  const float* cpb_w1 = (const float*)d_in[6];
  const float* cpb_b1 = (const float*)d_in[7];
  const float* cpb_w2 = (const float*)d_in[8];
  const float* proj_w = (const float*)d_in[9];
  const float* proj_b = (const float*)d_in[10];
  const float* table  = (const float*)d_in[11];
  const int*   relidx = (const int*)d_in[12];

  char* ws = (char*)d_ws;
  bf16* qkvb   = (bf16*)(ws + OFF_QKV);
  bf16* xb     = (bf16*)(ws + OFF_XB);   // x_bf16, then reused as attn_out
  bf16* wqkv   = (bf16*)(ws + OFF_WQKV);
  bf16* wproj  = (bf16*)(ws + OFF_WPROJ);
  float* btab  = (float*)(ws + OFF_BT);
  float* rbias = (float*)(ws + OFF_RB);

  cvt_f32_bf16<<<16384, 256, 0, stream>>>(x, xb, 65536 * 512 / 8);
  cvt_f32_bf16<<<384, 256, 0, stream>>>(qkv_w, wqkv, 1536 * 512 / 8);
  cvt_f32_bf16<<<128, 256, 0, stream>>>(proj_w, wproj, 512 * 512 / 8);
  cpb_mlp<<<225, 256, 0, stream>>>(table, cpb_w1, cpb_b1, cpb_w2, btab);
  cpb_gather<<<256, 256, 0, stream>>>(btab, relidx, rbias);

  // QKV = x_bf16 @ qkv_w^T + [q_bias|0|v_bias]  -> bf16 [65536][1536]
  gemm_bt<1536, true><<<256 * 12, 512, 0, stream>>>(xb, wqkv, (void*)qkvb, q_bias, v_bias);
  // fused cosine attention + bias + mask + softmax + PV -> bf16 [65536][512] (reuses xb)
  attn_kernel<<<16384, 256, 0, stream>>>(qkvb, mask, lsc, rbias, xb);
  // out = attn_out @ proj_w^T + proj_b -> fp32
  gemm_bt<512, false><<<256 * 4, 512, 0, stream>>>(xb, wproj, d_out, proj_b, nullptr);
}

// Round 3
// 540.717 us; speedup vs baseline: 1.1257x; 1.1257x over previous
//
#include <hip/hip_runtime.h>
#include <hip/hip_bf16.h>

typedef __bf16 bf16;
typedef __bf16 bf16x4 __attribute__((ext_vector_type(4)));
typedef __bf16 bf16x8 __attribute__((ext_vector_type(8)));
typedef float floatx4 __attribute__((ext_vector_type(4)));

#define MFMA16(a, b, c) __builtin_amdgcn_mfma_f32_16x16x32_bf16((a), (b), (c), 0, 0, 0)

// ---- workspace layout (bytes) ----
static constexpr long OFF_QKV   = 0;            // bf16 [65536][1536]  201326592
static constexpr long OFF_XB    = 201326592;    // bf16 [65536][512]   67108864 (x_bf16, later attn_out)
static constexpr long OFF_WQKV  = 268435456;    // bf16 [1536][512]    1572864
static constexpr long OFF_WPROJ = 270008320;    // bf16 [512][512]     524288
static constexpr long OFF_BT    = 270532608;    // f32  [225][16]      (padded to 16384)
static constexpr long OFF_RB    = 270548992;    // f32  [16][64][64]   262144
// total ~258.3 MB

__device__ __forceinline__ void load_lds16(const bf16* g, bf16* l) {
  // async global->LDS, 16B per lane; LDS dest is wave-uniform base + lane*16
  __builtin_amdgcn_global_load_lds((const __attribute__((address_space(1))) void*)(g),
                                   (__attribute__((address_space(3))) void*)(l), 16, 0, 0);
}

// ---------------- fp32 -> bf16 convert (8 elems/thread) ----------------
__global__ __launch_bounds__(256) void cvt_f32_bf16(const float* __restrict__ src,
                                                    bf16* __restrict__ dst, int n8) {
  int i = blockIdx.x * 256 + threadIdx.x;
  if (i < n8) {
    const float4* s = (const float4*)src;
    float4 a = s[2 * i], b = s[2 * i + 1];
    bf16x8 o;
    o[0] = (bf16)a.x; o[1] = (bf16)a.y; o[2] = (bf16)a.z; o[3] = (bf16)a.w;
    o[4] = (bf16)b.x; o[5] = (bf16)b.y; o[6] = (bf16)b.z; o[7] = (bf16)b.w;
    ((bf16x8*)dst)[i] = o;
  }
}

// ---------------- CPB-MLP: bias_table[225][16] ----------------
__global__ __launch_bounds__(256) void cpb_mlp(const float* __restrict__ table,
                                               const float* __restrict__ w1,
                                               const float* __restrict__ b1,
                                               const float* __restrict__ w2,
                                               float* __restrict__ bias_table) {
  __shared__ float hid[512];
  const int e = blockIdx.x;                   // 0..224
  const float t0 = table[e * 2 + 0], t1 = table[e * 2 + 1];
  for (int j = threadIdx.x; j < 512; j += 256) {
    float hv = t0 * w1[j * 2 + 0] + t1 * w1[j * 2 + 1] + b1[j];
    hid[j] = hv > 0.f ? hv : 0.f;
  }
  __syncthreads();
  const int hd = threadIdx.x >> 4, l = threadIdx.x & 15;
  float p = 0.f;
  for (int j = l; j < 512; j += 16) p += hid[j] * w2[hd * 512 + j];
  #pragma unroll
  for (int d = 8; d >= 1; d >>= 1) p += __shfl_xor(p, d, 16);
  if (l == 0) bias_table[e * 16 + hd] = p;
}

// ---------------- gather + sigmoid: rel_bias[16][64][64] ----------------
__global__ __launch_bounds__(256) void cpb_gather(const float* __restrict__ bias_table,
                                                  const int* __restrict__ idx,
                                                  float* __restrict__ rel_bias) {
  int f = blockIdx.x * 256 + threadIdx.x;     // 65536 total
  int h = f >> 12, ij = f & 4095;
  float v = bias_table[idx[ij] * 16 + h];
  rel_bias[f] = 16.f / (1.f + __expf(-v));
}

// ---------------- bf16 GEMM: C[M,NN] = A[M,512] @ Bt[NN,512]^T (+bias) ----------------
// R3: 256x256 8-phase template (m201 structure) in plain HIP.
//  - 8 waves (512 thr), per-wave output 128x64 (LDS bytes/FLOP 1/42.7 vs 1/32 at 64x64:
//    the 128^2 structure was LDS-read-bound, MfmaUtil ~23%).
//  - LDS: 4-slot ring per operand, slot = 256 rows x 32 k = 16 KB; 128 KB total.
//    K=512 = 16 k-slices; slice h lives in slot h&3; staged 3 slices (6 phases) ahead;
//    slot overwrite always separated from its last read by a phase barrier.
//  - COUNTED vmcnt(8) once per slice: slice h+1 proven landed, slices h+2/h+3 (8 loads)
//    stay IN FLIGHT across s_barrier (T4). Never drains to 0 until the tail.
//  - 2 phases/slice: (h,0) stage A(h+3), read 8 A-frags + 2 B-frags, 16 MFMA (n 0,1);
//    (h,1) stage B(h+3), read 2 B-frags, 16 MFMA (n 2,3). setprio(1) around MFMA (T5),
//    sched_barrier(0) pins each phase (rule 18).
//  - Swizzle: stored k-group = logical ^ ((row>>1)&3) -> uniform bank load on
//    ds_read_b128; global source pre-swizzled so linear gload_lds lands it (rule 21).
//  - Grid: n-INNERMOST per XCD chunk (R2's m-innermost caused 10x A re-fetch, 399 MB).
template <int NN, bool QKV>
__global__ __launch_bounds__(512, 2) void gemm_bt(const bf16* __restrict__ A,
                                                  const bf16* __restrict__ Bt,
                                                  void* __restrict__ outv,
                                                  const float* __restrict__ bias_a,
                                                  const float* __restrict__ bias_b) {
  constexpr int K = 512;
  constexpr int nblk = NN / 256;
  __shared__ alignas(16) bf16 As[4][8192];   // 64 KB: slot = 256 rows x 32 k
  __shared__ alignas(16) bf16 Bs[4][8192];   // 64 KB
  const int tid = threadIdx.x;
  const int lane = tid & 63;
  const int wv = tid >> 6;                // 0..7
  const int bid = blockIdx.x;
  const int xcd = bid & 7;
  const int g = bid >> 3;                 // 0 .. 256*nblk/8 - 1
  const int mb = xcd * 32 + g / nblk;     // n innermost: A-slab shared by nblk blocks
  const int nb = g % nblk;
  const long m0 = (long)mb * 256;
  const int n0 = nb * 256;
  const int wm = (wv >> 2) * 128;         // 2 M-waves
  const int wn = (wv & 3) * 64;           // 4 N-waves
  const int cl = lane & 15;
  const int cq = lane >> 4;
  const int wbase = tid & ~63;
  // per-thread constant read swizzle: xor k-group with (row>>1)&3 == (cl>>1)&3
  const int sx = (cq ^ ((cl >> 1) & 3)) << 3;   // elem offset of 16B group

  const floatx4 fzero = {0.f, 0.f, 0.f, 0.f};
  floatx4 acc[8][4];
  #pragma unroll
  for (int i = 0; i < 8; ++i)
    #pragma unroll
    for (int j = 0; j < 4; ++j) acc[i][j] = fzero;

  auto stageA = [&](int kh) {
    #pragma unroll
    for (int o = 0; o < 2; ++o) {
      const int s = o * 512 + tid;
      const int r = s >> 2;                       // 0..255
      const int gl = (s & 3) ^ ((s >> 3) & 3);    // logical k-group (involution)
      const bf16* ga = A + (m0 + r) * (long)K + kh * 32 + gl * 8;
      load_lds16(ga, &As[kh & 3][(o * 512 + wbase) * 8]);
    }
  };
  auto stageB = [&](int kh) {
    #pragma unroll
    for (int o = 0; o < 2; ++o) {
      const int s = o * 512 + tid;
      const int r = s >> 2;
      const int gl = (s & 3) ^ ((s >> 3) & 3);
      const bf16* gb = Bt + (long)(n0 + r) * K + kh * 32 + gl * 8;
      load_lds16(gb, &Bs[kh & 3][(o * 512 + wbase) * 8]);
    }
  };
  auto waitvm = [&](int n) {
    if (n == 8) asm volatile("s_waitcnt vmcnt(8)" ::: "memory");
    else if (n == 4) asm volatile("s_waitcnt vmcnt(4)" ::: "memory");
    else if (n == 0) asm volatile("s_waitcnt vmcnt(0)" ::: "memory");
  };

  // one k-slice = 2 phases
  auto kstep = [&](int h, int slot, bool doStage, int vmN, bool lastH) {
    bf16x8 af[8];
    // ---- phase (h,0): stage A(h+3); read A-frags + B n-frags 0,1; 16 MFMA
    if (doStage) stageA(h + 3);
    #pragma unroll
    for (int m = 0; m < 8; ++m) {
      const int r = wm + m * 16 + cl;
      af[m] = *(const bf16x8*)&As[slot][r * 32 + sx];
    }
    bf16x8 b0[2];
    #pragma unroll
    for (int n = 0; n < 2; ++n) {
      const int r = wn + n * 16 + cl;
      b0[n] = *(const bf16x8*)&Bs[slot][r * 32 + sx];
    }
    __builtin_amdgcn_s_setprio(1);
    #pragma unroll
    for (int i = 0; i < 8; ++i) {
      acc[i][0] = MFMA16(b0[0], af[i], acc[i][0]);   // swapped: col-vector C layout
      acc[i][1] = MFMA16(b0[1], af[i], acc[i][1]);
    }
    __builtin_amdgcn_s_setprio(0);
    __builtin_amdgcn_sched_barrier(0);
    __builtin_amdgcn_s_barrier();
    // ---- phase (h,1): stage B(h+3); read B n-frags 2,3; 16 MFMA
    if (doStage) stageB(h + 3);
    bf16x8 b1[2];
    #pragma unroll
    for (int n = 0; n < 2; ++n) {
      const int r = wn + (2 + n) * 16 + cl;
      b1[n] = *(const bf16x8*)&Bs[slot][r * 32 + sx];
    }
    __builtin_amdgcn_s_setprio(1);
    #pragma unroll
    for (int i = 0; i < 8; ++i) {
      acc[i][2] = MFMA16(b1[0], af[i], acc[i][2]);
      acc[i][3] = MFMA16(b1[1], af[i], acc[i][3]);
    }
    __builtin_amdgcn_s_setprio(0);
    __builtin_amdgcn_sched_barrier(0);
    waitvm(vmN);                       // slice h+1 landed; h+2,h+3 stay in flight
    if (!lastH) __builtin_amdgcn_s_barrier();
  };

  // prologue: slices 0,1,2 issued; wait slice 0 (8 newest = slices 1,2 in flight)
  stageA(0); stageB(0); stageA(1); stageB(1); stageA(2); stageB(2);
  asm volatile("s_waitcnt vmcnt(8)" ::: "memory");
  __builtin_amdgcn_s_barrier();

  #pragma unroll 4
  for (int h = 0; h < 12; ++h) kstep(h, h & 3, true, 8, false);
  kstep(12, 0, true, 8, false);    // stages slice 15 (last)
  kstep(13, 1, false, 4, false);   // slice 14 landed; 15 in flight
  kstep(14, 2, false, 0, false);   // slice 15 landed
  kstep(15, 3, false, -1, true);

  // epilogue: lane holds C[m0+wm+i*16+cl][n0+wn+j*16+cq*4 + r], r=0..3 consecutive cols
  const int cq4 = cq * 4;
  #pragma unroll
  for (int i = 0; i < 8; ++i) {
    const long m = m0 + wm + i * 16 + cl;
    #pragma unroll
    for (int j = 0; j < 4; ++j) {
      const int nbase = n0 + wn + j * 16 + cq4;
      if constexpr (QKV) {
        // qkv bias: [q_bias | zeros | v_bias]; 4-col group never straddles a boundary
        float4 bb = {0.f, 0.f, 0.f, 0.f};
        if (nbase < 512) bb = *(const float4*)&bias_a[nbase];
        else if (nbase >= 1024) bb = *(const float4*)&bias_b[nbase - 1024];
        bf16x4 o;
        o[0] = (bf16)(acc[i][j][0] + bb.x);
        o[1] = (bf16)(acc[i][j][1] + bb.y);
        o[2] = (bf16)(acc[i][j][2] + bb.z);
        o[3] = (bf16)(acc[i][j][3] + bb.w);
        *(bf16x4*)((bf16*)outv + m * NN + nbase) = o;
      } else {
        const float4 bb = *(const float4*)&bias_a[nbase];
        float4 o;
        o.x = acc[i][j][0] + bb.x;
        o.y = acc[i][j][1] + bb.y;
        o.z = acc[i][j][2] + bb.z;
        o.w = acc[i][j][3] + bb.w;
        *(float4*)((float*)outv + m * NN + nbase) = o;
      }
    }
  }
}

// ---------------- fused window attention: one block per (window, head) ----------------
// Head-pair XCD swizzle: (b,2j) and (b,2j+1) share 128B qkv cachelines; keep them on
// the same XCD, adjacent in dispatch order, so the second block hits L2.
// LDS pool 24.5KB (P aliases qh/ql after a barrier) -> 5-6 blocks/CU by LDS.
__global__ __launch_bounds__(256, 5) void attn_kernel(const bf16* __restrict__ qkv,
                                                      const float* __restrict__ mask,
                                                      const float* __restrict__ lscale,
                                                      const float* __restrict__ rel_bias,
                                                      bf16* __restrict__ out) {
  const int bid = blockIdx.x;
  const int xcd = bid & 7;
  const int t = bid >> 3;                  // 0..2047
  const int p = xcd + ((t >> 1) << 3);     // pair index 0..8191
  const int b = p >> 3;                    // window 0..1023
  const int h = ((p & 7) << 1) | (t & 1);  // head 0..15
  const int wi = b & 63;
  const int tid = threadIdx.x;
  const int lane = tid & 63;
  const int wv = tid >> 6;
  const int cl = lane & 15;
  const int cq = lane >> 4;

  // single pool: qh/ql/kh/kl [64x40] each, vT [32x72]; ps [64x72] aliases qh+ql
  __shared__ alignas(16) bf16 smem[12544];  // 25088 B
  bf16* qh_s = smem;            // 2560 elems
  bf16* ql_s = smem + 2560;
  bf16* kh_s = smem + 5120;
  bf16* kl_s = smem + 7680;
  bf16* vT   = smem + 10240;    // 2304 elems
  bf16* ps   = smem;            // 4608 elems, reused after barrier

  {  // stage + l2-normalize q,k (fp32 norm, hi/lo bf16 split); transpose v
    const int r = tid >> 2, seg = tid & 3;
    const bf16* base = qkv + (long)(b * 64 + r) * 1536 + h * 32 + seg * 8;
    float f[8], ss;
    bf16x8 hi, lo;

    bf16x8 qv = *(const bf16x8*)(base);
    ss = 0.f;
    #pragma unroll
    for (int j = 0; j < 8; ++j) { f[j] = (float)qv[j]; ss += f[j] * f[j]; }
    ss += __shfl_xor(ss, 1, 4); ss += __shfl_xor(ss, 2, 4);
    float s1 = 1.f / fmaxf(sqrtf(ss), 1e-12f);
    #pragma unroll
    for (int j = 0; j < 8; ++j) {
      float xn = f[j] * s1;
      bf16 xh = (bf16)xn;
      hi[j] = xh; lo[j] = (bf16)(xn - (float)xh);
    }
    *(bf16x8*)&qh_s[r * 40 + seg * 8] = hi;
    *(bf16x8*)&ql_s[r * 40 + seg * 8] = lo;

    bf16x8 kv = *(const bf16x8*)(base + 512);
    ss = 0.f;
    #pragma unroll
    for (int j = 0; j < 8; ++j) { f[j] = (float)kv[j]; ss += f[j] * f[j]; }
    ss += __shfl_xor(ss, 1, 4); ss += __shfl_xor(ss, 2, 4);
    s1 = 1.f / fmaxf(sqrtf(ss), 1e-12f);
    #pragma unroll
    for (int j = 0; j < 8; ++j) {
      float xn = f[j] * s1;
      bf16 xh = (bf16)xn;
      hi[j] = xh; lo[j] = (bf16)(xn - (float)xh);
    }
    *(bf16x8*)&kh_s[r * 40 + seg * 8] = hi;
    *(bf16x8*)&kl_s[r * 40 + seg * 8] = lo;

    bf16x8 vv = *(const bf16x8*)(base + 1024);
    #pragma unroll
    for (int j = 0; j < 8; ++j) vT[(seg * 8 + j) * 72 + r] = vv[j];
  }
  __syncthreads();

  const float sc = __expf(fminf(lscale[h], 4.6051701859880914f));  // exp(min(ls, ln 100))

  // QK^T for this wave's 16-row m-tile; 3-MFMA split-bf16 for accuracy
  const int mrow = wv * 16 + cl;
  const bf16x8 aqh = *(const bf16x8*)&qh_s[mrow * 40 + cq * 8];
  const bf16x8 aql = *(const bf16x8*)&ql_s[mrow * 40 + cq * 8];
  floatx4 sacc[4];
  #pragma unroll
  for (int nt = 0; nt < 4; ++nt) {
    const int nr = nt * 16 + cl;
    const bf16x8 bkh = *(const bf16x8*)&kh_s[nr * 40 + cq * 8];
    const bf16x8 bkl = *(const bf16x8*)&kl_s[nr * 40 + cq * 8];
    floatx4 a = {0.f, 0.f, 0.f, 0.f};
    a = MFMA16(aql, bkh, a);
    a = MFMA16(aqh, bkl, a);
    a = MFMA16(aqh, bkh, a);
    sacc[nt] = a;
  }
  __syncthreads();  // all waves done reading qh/ql/kh/kl before ps overwrites them

  // scale + rel_bias + mask, fp32 softmax over 64 cols (16 lanes x 4 nt)
  float pw[4][4];  // [rg][nt]
  #pragma unroll
  for (int rg = 0; rg < 4; ++rg) {
    const int row = wv * 16 + cq * 4 + rg;
    const float* rbp = rel_bias + h * 4096 + row * 64;
    const float* mkp = mask + wi * 4096 + row * 64;
    float mxv = -1e30f;
    #pragma unroll
    for (int nt = 0; nt < 4; ++nt) {
      float s = sacc[nt][rg] * sc + rbp[nt * 16 + cl] + mkp[nt * 16 + cl];
      pw[rg][nt] = s;
      mxv = fmaxf(mxv, s);
    }
    #pragma unroll
    for (int d = 8; d >= 1; d >>= 1) mxv = fmaxf(mxv, __shfl_xor(mxv, d, 16));
    float sm = 0.f;
    #pragma unroll
    for (int nt = 0; nt < 4; ++nt) {
      float e = __expf(pw[rg][nt] - mxv);
      pw[rg][nt] = e;
      sm += e;
    }
    #pragma unroll
    for (int d = 8; d >= 1; d >>= 1) sm += __shfl_xor(sm, d, 16);
    const float inv = 1.f / sm;
    #pragma unroll
    for (int nt = 0; nt < 4; ++nt)
      ps[row * 72 + nt * 16 + cl] = (bf16)(pw[rg][nt] * inv);
  }
  // no barrier needed: each wave reads back only its own 16 P-rows (within-wave lgkmcnt)

  // PV: O[64x32] = P[64x64] @ V[64x32] via vT; operands SWAPPED so each lane holds
  // 4 consecutive head-dims of one row -> 2x bf16x4 stores instead of 8 scalar
  floatx4 oacc[2];
  oacc[0] = (floatx4){0.f, 0.f, 0.f, 0.f};
  oacc[1] = (floatx4){0.f, 0.f, 0.f, 0.f};
  #pragma unroll
  for (int ks = 0; ks < 2; ++ks) {
    const bf16x8 ap = *(const bf16x8*)&ps[(wv * 16 + cl) * 72 + ks * 32 + cq * 8];
    #pragma unroll
    for (int nt = 0; nt < 2; ++nt) {
      const bf16x8 bv = *(const bf16x8*)&vT[(nt * 16 + cl) * 72 + ks * 32 + cq * 8];
      oacc[nt] = MFMA16(bv, ap, oacc[nt]);  // swapped: O^T fragment
    }
  }
  // lane holds O[wv*16 + cl][nt*16 + cq*4 + r]
  const long obase = (long)(b * 64 + wv * 16 + cl) * 512 + h * 32 + cq * 4;
  #pragma unroll
  for (int nt = 0; nt < 2; ++nt) {
    bf16x4 o;
    #pragma unroll
    for (int r = 0; r < 4; ++r) o[r] = (bf16)oacc[nt][r];
    *(bf16x4*)&out[obase + nt * 16] = o;
  }
}

extern "C" void kernel_launch(void* const* d_in, const int* in_sizes, int n_in,
                              void* d_out, int out_size, void* d_ws, size_t ws_size,
                              hipStream_t stream) {
  const float* x      = (const float*)d_in[0];
  const float* mask   = (const float*)d_in[1];
  const float* qkv_w  = (const float*)d_in[2];
  const float* q_bias = (const float*)d_in[3];
  const float* v_bias = (const float*)d_in[4];
  const float* lsc    = (const float*)d_in[5];
  const float* cpb_w1 = (const float*)d_in[6];
  const float* cpb_b1 = (const float*)d_in[7];
  const float* cpb_w2 = (const float*)d_in[8];
  const float* proj_w = (const float*)d_in[9];
  const float* proj_b = (const float*)d_in[10];
  const float* table  = (const float*)d_in[11];
  const int*   relidx = (const int*)d_in[12];

  char* ws = (char*)d_ws;
  bf16* qkvb   = (bf16*)(ws + OFF_QKV);
  bf16* xb     = (bf16*)(ws + OFF_XB);   // x_bf16, then reused as attn_out
  bf16* wqkv   = (bf16*)(ws + OFF_WQKV);
  bf16* wproj  = (bf16*)(ws + OFF_WPROJ);
  float* btab  = (float*)(ws + OFF_BT);
  float* rbias = (float*)(ws + OFF_RB);

  cvt_f32_bf16<<<16384, 256, 0, stream>>>(x, xb, 65536 * 512 / 8);
  cvt_f32_bf16<<<384, 256, 0, stream>>>(qkv_w, wqkv, 1536 * 512 / 8);
  cvt_f32_bf16<<<128, 256, 0, stream>>>(proj_w, wproj, 512 * 512 / 8);
  cpb_mlp<<<225, 256, 0, stream>>>(table, cpb_w1, cpb_b1, cpb_w2, btab);
  cpb_gather<<<256, 256, 0, stream>>>(btab, relidx, rbias);

  // QKV = x_bf16 @ qkv_w^T + [q_bias|0|v_bias]  -> bf16 [65536][1536]
  gemm_bt<1536, true><<<1536, 512, 0, stream>>>(xb, wqkv, (void*)qkvb, q_bias, v_bias);
  // fused cosine attention + bias + mask + softmax + PV -> bf16 [65536][512] (reuses xb)
  attn_kernel<<<16384, 256, 0, stream>>>(qkvb, mask, lsc, rbias, xb);
  // out = attn_out @ proj_w^T + proj_b -> fp32
  gemm_bt<512, false><<<512, 512, 0, stream>>>(xb, wproj, d_out, proj_b, nullptr);
}

// Round 4
// 540.128 us; speedup vs baseline: 1.1270x; 1.0011x over previous
//
#include <hip/hip_runtime.h>
#include <hip/hip_bf16.h>

typedef __bf16 bf16;
typedef __bf16 bf16x4 __attribute__((ext_vector_type(4)));
typedef __bf16 bf16x8 __attribute__((ext_vector_type(8)));
typedef float floatx4 __attribute__((ext_vector_type(4)));

#define MFMA16(a, b, c) __builtin_amdgcn_mfma_f32_16x16x32_bf16((a), (b), (c), 0, 0, 0)

// ---- workspace layout (bytes) ----
static constexpr long OFF_QKV   = 0;            // bf16 [65536][1536]  201326592
static constexpr long OFF_XB    = 201326592;    // bf16 [65536][512]   67108864 (x_bf16, later attn_out)
static constexpr long OFF_WQKV  = 268435456;    // bf16 [1536][512]    1572864
static constexpr long OFF_WPROJ = 270008320;    // bf16 [512][512]     524288
static constexpr long OFF_BT    = 270532608;    // f32  [225][16]      (padded to 16384)
static constexpr long OFF_RB    = 270548992;    // f32  [16][64][64]   262144
// total ~258.3 MB

__device__ __forceinline__ void load_lds16(const bf16* g, bf16* l) {
  // async global->LDS, 16B per lane; LDS dest is wave-uniform base + lane*16
  __builtin_amdgcn_global_load_lds((const __attribute__((address_space(1))) void*)(g),
                                   (__attribute__((address_space(3))) void*)(l), 16, 0, 0);
}

// ---------------- fp32 -> bf16 convert (8 elems/thread) ----------------
__global__ __launch_bounds__(256) void cvt_f32_bf16(const float* __restrict__ src,
                                                    bf16* __restrict__ dst, int n8) {
  int i = blockIdx.x * 256 + threadIdx.x;
  if (i < n8) {
    const float4* s = (const float4*)src;
    float4 a = s[2 * i], b = s[2 * i + 1];
    bf16x8 o;
    o[0] = (bf16)a.x; o[1] = (bf16)a.y; o[2] = (bf16)a.z; o[3] = (bf16)a.w;
    o[4] = (bf16)b.x; o[5] = (bf16)b.y; o[6] = (bf16)b.z; o[7] = (bf16)b.w;
    ((bf16x8*)dst)[i] = o;
  }
}

// ---------------- CPB-MLP: bias_table[225][16] ----------------
__global__ __launch_bounds__(256) void cpb_mlp(const float* __restrict__ table,
                                               const float* __restrict__ w1,
                                               const float* __restrict__ b1,
                                               const float* __restrict__ w2,
                                               float* __restrict__ bias_table) {
  __shared__ float hid[512];
  const int e = blockIdx.x;                   // 0..224
  const float t0 = table[e * 2 + 0], t1 = table[e * 2 + 1];
  for (int j = threadIdx.x; j < 512; j += 256) {
    float hv = t0 * w1[j * 2 + 0] + t1 * w1[j * 2 + 1] + b1[j];
    hid[j] = hv > 0.f ? hv : 0.f;
  }
  __syncthreads();
  const int hd = threadIdx.x >> 4, l = threadIdx.x & 15;
  float p = 0.f;
  for (int j = l; j < 512; j += 16) p += hid[j] * w2[hd * 512 + j];
  #pragma unroll
  for (int d = 8; d >= 1; d >>= 1) p += __shfl_xor(p, d, 16);
  if (l == 0) bias_table[e * 16 + hd] = p;
}

// ---------------- gather + sigmoid: rel_bias[16][64][64] ----------------
__global__ __launch_bounds__(256) void cpb_gather(const float* __restrict__ bias_table,
                                                  const int* __restrict__ idx,
                                                  float* __restrict__ rel_bias) {
  int f = blockIdx.x * 256 + threadIdx.x;     // 65536 total
  int h = f >> 12, ij = f & 4095;
  float v = bias_table[idx[ij] * 16 + h];
  rel_bias[f] = 16.f / (1.f + __expf(-v));
}

// ---------------- bf16 GEMM: C[M,NN] = A[M,512] @ Bt[NN,512]^T (+bias) ----------------
// R4: 256x256, 8 waves, 4-slot ring (slot = 256 rows x 32 k = 16 KB; 128 KB total),
// ONE merged phase per k-slice (R3 had 2 phases/slice = 32 lockstep barriers/block;
// MfmaUtil stuck at 26.6% with everything else idle => barrier-lockstep overhead at
// 1 block/CU). Per slice: {issue stage(h+3) A+B; 4 B-reads + 8 A-reads (ds_read_b128,
// XOR-swizzled, 0 conflicts); 32 MFMA with setprio; counted vmcnt(8); s_barrier}.
// Ring safety with single barrier: stage(h+3) overwrites slot of slice h-1, whose last
// read precedes the barrier that ended slice h-1; stages issue only after that barrier.
// Counted vmcnt (T4): slice h+1 proven landed, h+2/h+3 (8 loads) stay in flight across
// the barrier; never drains to 0 until the tail. Grid: n-innermost per XCD chunk.
template <int NN, bool QKV>
__global__ __launch_bounds__(512, 2) void gemm_bt(const bf16* __restrict__ A,
                                                  const bf16* __restrict__ Bt,
                                                  void* __restrict__ outv,
                                                  const float* __restrict__ bias_a,
                                                  const float* __restrict__ bias_b) {
  constexpr int K = 512;
  constexpr int nblk = NN / 256;
  __shared__ alignas(16) bf16 As[4][8192];   // 64 KB: slot = 256 rows x 32 k
  __shared__ alignas(16) bf16 Bs[4][8192];   // 64 KB
  const int tid = threadIdx.x;
  const int lane = tid & 63;
  const int wv = tid >> 6;                // 0..7
  const int bid = blockIdx.x;
  const int xcd = bid & 7;
  const int g = bid >> 3;                 // 0 .. 256*nblk/8 - 1
  const int mb = xcd * 32 + g / nblk;     // n innermost: A-slab shared by nblk blocks
  const int nb = g % nblk;
  const long m0 = (long)mb * 256;
  const int n0 = nb * 256;
  const int wm = (wv >> 2) * 128;         // 2 M-waves
  const int wn = (wv & 3) * 64;           // 4 N-waves
  const int cl = lane & 15;
  const int cq = lane >> 4;
  const int wbase = tid & ~63;
  // per-thread constant read swizzle: xor k-group with (row>>1)&3 == (cl>>1)&3
  const int sx = (cq ^ ((cl >> 1) & 3)) << 3;   // elem offset of 16B group

  const floatx4 fzero = {0.f, 0.f, 0.f, 0.f};
  floatx4 acc[8][4];
  #pragma unroll
  for (int i = 0; i < 8; ++i)
    #pragma unroll
    for (int j = 0; j < 4; ++j) acc[i][j] = fzero;

  auto stageA = [&](int kh) {
    #pragma unroll
    for (int o = 0; o < 2; ++o) {
      const int s = o * 512 + tid;
      const int r = s >> 2;                       // 0..255
      const int gl = (s & 3) ^ ((s >> 3) & 3);    // logical k-group (involution)
      const bf16* ga = A + (m0 + r) * (long)K + kh * 32 + gl * 8;
      load_lds16(ga, &As[kh & 3][(o * 512 + wbase) * 8]);
    }
  };
  auto stageB = [&](int kh) {
    #pragma unroll
    for (int o = 0; o < 2; ++o) {
      const int s = o * 512 + tid;
      const int r = s >> 2;
      const int gl = (s & 3) ^ ((s >> 3) & 3);
      const bf16* gb = Bt + (long)(n0 + r) * K + kh * 32 + gl * 8;
      load_lds16(gb, &Bs[kh & 3][(o * 512 + wbase) * 8]);
    }
  };

  // one k-slice = ONE phase: stage; read 4B+8A; 32 MFMA; counted vmcnt; barrier
  auto kstep = [&](int h, int slot, bool doStage, int vmN, bool lastH) {
    if (doStage) { stageA(h + 3); stageB(h + 3); }
    bf16x8 bfr[4], af[8];
    #pragma unroll
    for (int n = 0; n < 4; ++n) {
      const int r = wn + n * 16 + cl;
      bfr[n] = *(const bf16x8*)&Bs[slot][r * 32 + sx];
    }
    #pragma unroll
    for (int m = 0; m < 8; ++m) {
      const int r = wm + m * 16 + cl;
      af[m] = *(const bf16x8*)&As[slot][r * 32 + sx];
    }
    __builtin_amdgcn_s_setprio(1);
    #pragma unroll
    for (int i = 0; i < 8; ++i)
      #pragma unroll
      for (int j = 0; j < 4; ++j)
        acc[i][j] = MFMA16(bfr[j], af[i], acc[i][j]);   // swapped: col-vector C layout
    __builtin_amdgcn_s_setprio(0);
    __builtin_amdgcn_sched_barrier(0);
    if (vmN == 8)      asm volatile("s_waitcnt vmcnt(8)" ::: "memory");
    else if (vmN == 4) asm volatile("s_waitcnt vmcnt(4)" ::: "memory");
    else if (vmN == 0) asm volatile("s_waitcnt vmcnt(0)" ::: "memory");
    if (!lastH) __builtin_amdgcn_s_barrier();
  };

  // prologue: slices 0,1,2 issued; wait slice 0 (8 newest = slices 1,2 in flight)
  stageA(0); stageB(0); stageA(1); stageB(1); stageA(2); stageB(2);
  asm volatile("s_waitcnt vmcnt(8)" ::: "memory");
  __builtin_amdgcn_s_barrier();

  #pragma unroll 4
  for (int h = 0; h < 12; ++h) kstep(h, h & 3, true, 8, false);
  kstep(12, 0, true, 8, false);    // stages slice 15 (last)
  kstep(13, 1, false, 4, false);   // slice 14 landed; 15 in flight
  kstep(14, 2, false, 0, false);   // slice 15 landed
  kstep(15, 3, false, -1, true);

  // epilogue: lane holds C[m0+wm+i*16+cl][n0+wn+j*16+cq*4 + r], r=0..3 consecutive cols
  const int cq4 = cq * 4;
  #pragma unroll
  for (int i = 0; i < 8; ++i) {
    const long m = m0 + wm + i * 16 + cl;
    #pragma unroll
    for (int j = 0; j < 4; ++j) {
      const int nbase = n0 + wn + j * 16 + cq4;
      if constexpr (QKV) {
        // qkv bias: [q_bias | zeros | v_bias]; 4-col group never straddles a boundary
        float4 bb = {0.f, 0.f, 0.f, 0.f};
        if (nbase < 512) bb = *(const float4*)&bias_a[nbase];
        else if (nbase >= 1024) bb = *(const float4*)&bias_b[nbase - 1024];
        bf16x4 o;
        o[0] = (bf16)(acc[i][j][0] + bb.x);
        o[1] = (bf16)(acc[i][j][1] + bb.y);
        o[2] = (bf16)(acc[i][j][2] + bb.z);
        o[3] = (bf16)(acc[i][j][3] + bb.w);
        *(bf16x4*)((bf16*)outv + m * NN + nbase) = o;
      } else {
        const float4 bb = *(const float4*)&bias_a[nbase];
        float4 o;
        o.x = acc[i][j][0] + bb.x;
        o.y = acc[i][j][1] + bb.y;
        o.z = acc[i][j][2] + bb.z;
        o.w = acc[i][j][3] + bb.w;
        *(float4*)((float*)outv + m * NN + nbase) = o;
      }
    }
  }
}

// ---------------- fused window attention: one block per (window, head) ----------------
// Head-pair XCD swizzle: (b,2j) and (b,2j+1) share 128B qkv cachelines; keep them on
// the same XCD, adjacent in dispatch order, so the second block hits L2.
// LDS pool 24.5KB (P aliases qh/ql after a barrier) -> 5-6 blocks/CU by LDS.
__global__ __launch_bounds__(256, 5) void attn_kernel(const bf16* __restrict__ qkv,
                                                      const float* __restrict__ mask,
                                                      const float* __restrict__ lscale,
                                                      const float* __restrict__ rel_bias,
                                                      bf16* __restrict__ out) {
  const int bid = blockIdx.x;
  const int xcd = bid & 7;
  const int t = bid >> 3;                  // 0..2047
  const int p = xcd + ((t >> 1) << 3);     // pair index 0..8191
  const int b = p >> 3;                    // window 0..1023
  const int h = ((p & 7) << 1) | (t & 1);  // head 0..15
  const int wi = b & 63;
  const int tid = threadIdx.x;
  const int lane = tid & 63;
  const int wv = tid >> 6;
  const int cl = lane & 15;
  const int cq = lane >> 4;

  // single pool: qh/ql/kh/kl [64x40] each, vT [32x72]; ps [64x72] aliases qh+ql
  __shared__ alignas(16) bf16 smem[12544];  // 25088 B
  bf16* qh_s = smem;            // 2560 elems
  bf16* ql_s = smem + 2560;
  bf16* kh_s = smem + 5120;
  bf16* kl_s = smem + 7680;
  bf16* vT   = smem + 10240;    // 2304 elems
  bf16* ps   = smem;            // 4608 elems, reused after barrier

  {  // stage + l2-normalize q,k (fp32 norm, hi/lo bf16 split); transpose v
    const int r = tid >> 2, seg = tid & 3;
    const bf16* base = qkv + (long)(b * 64 + r) * 1536 + h * 32 + seg * 8;
    float f[8], ss;
    bf16x8 hi, lo;

    bf16x8 qv = *(const bf16x8*)(base);
    ss = 0.f;
    #pragma unroll
    for (int j = 0; j < 8; ++j) { f[j] = (float)qv[j]; ss += f[j] * f[j]; }
    ss += __shfl_xor(ss, 1, 4); ss += __shfl_xor(ss, 2, 4);
    float s1 = 1.f / fmaxf(sqrtf(ss), 1e-12f);
    #pragma unroll
    for (int j = 0; j < 8; ++j) {
      float xn = f[j] * s1;
      bf16 xh = (bf16)xn;
      hi[j] = xh; lo[j] = (bf16)(xn - (float)xh);
    }
    *(bf16x8*)&qh_s[r * 40 + seg * 8] = hi;
    *(bf16x8*)&ql_s[r * 40 + seg * 8] = lo;

    bf16x8 kv = *(const bf16x8*)(base + 512);
    ss = 0.f;
    #pragma unroll
    for (int j = 0; j < 8; ++j) { f[j] = (float)kv[j]; ss += f[j] * f[j]; }
    ss += __shfl_xor(ss, 1, 4); ss += __shfl_xor(ss, 2, 4);
    s1 = 1.f / fmaxf(sqrtf(ss), 1e-12f);
    #pragma unroll
    for (int j = 0; j < 8; ++j) {
      float xn = f[j] * s1;
      bf16 xh = (bf16)xn;
      hi[j] = xh; lo[j] = (bf16)(xn - (float)xh);
    }
    *(bf16x8*)&kh_s[r * 40 + seg * 8] = hi;
    *(bf16x8*)&kl_s[r * 40 + seg * 8] = lo;

    bf16x8 vv = *(const bf16x8*)(base + 1024);
    #pragma unroll
    for (int j = 0; j < 8; ++j) vT[(seg * 8 + j) * 72 + r] = vv[j];
  }
  __syncthreads();

  const float sc = __expf(fminf(lscale[h], 4.6051701859880914f));  // exp(min(ls, ln 100))

  // QK^T for this wave's 16-row m-tile; 3-MFMA split-bf16 for accuracy
  const int mrow = wv * 16 + cl;
  const bf16x8 aqh = *(const bf16x8*)&qh_s[mrow * 40 + cq * 8];
  const bf16x8 aql = *(const bf16x8*)&ql_s[mrow * 40 + cq * 8];
  floatx4 sacc[4];
  #pragma unroll
  for (int nt = 0; nt < 4; ++nt) {
    const int nr = nt * 16 + cl;
    const bf16x8 bkh = *(const bf16x8*)&kh_s[nr * 40 + cq * 8];
    const bf16x8 bkl = *(const bf16x8*)&kl_s[nr * 40 + cq * 8];
    floatx4 a = {0.f, 0.f, 0.f, 0.f};
    a = MFMA16(aql, bkh, a);
    a = MFMA16(aqh, bkl, a);
    a = MFMA16(aqh, bkh, a);
    sacc[nt] = a;
  }
  __syncthreads();  // all waves done reading qh/ql/kh/kl before ps overwrites them

  // scale + rel_bias + mask, fp32 softmax over 64 cols (16 lanes x 4 nt)
  float pw[4][4];  // [rg][nt]
  #pragma unroll
  for (int rg = 0; rg < 4; ++rg) {
    const int row = wv * 16 + cq * 4 + rg;
    const float* rbp = rel_bias + h * 4096 + row * 64;
    const float* mkp = mask + wi * 4096 + row * 64;
    float mxv = -1e30f;
    #pragma unroll
    for (int nt = 0; nt < 4; ++nt) {
      float s = sacc[nt][rg] * sc + rbp[nt * 16 + cl] + mkp[nt * 16 + cl];
      pw[rg][nt] = s;
      mxv = fmaxf(mxv, s);
    }
    #pragma unroll
    for (int d = 8; d >= 1; d >>= 1) mxv = fmaxf(mxv, __shfl_xor(mxv, d, 16));
    float sm = 0.f;
    #pragma unroll
    for (int nt = 0; nt < 4; ++nt) {
      float e = __expf(pw[rg][nt] - mxv);
      pw[rg][nt] = e;
      sm += e;
    }
    #pragma unroll
    for (int d = 8; d >= 1; d >>= 1) sm += __shfl_xor(sm, d, 16);
    const float inv = 1.f / sm;
    #pragma unroll
    for (int nt = 0; nt < 4; ++nt)
      ps[row * 72 + nt * 16 + cl] = (bf16)(pw[rg][nt] * inv);
  }
  // no barrier needed: each wave reads back only its own 16 P-rows (within-wave lgkmcnt)

  // PV: O[64x32] = P[64x64] @ V[64x32] via vT; operands SWAPPED so each lane holds
  // 4 consecutive head-dims of one row -> 2x bf16x4 stores instead of 8 scalar
  floatx4 oacc[2];
  oacc[0] = (floatx4){0.f, 0.f, 0.f, 0.f};
  oacc[1] = (floatx4){0.f, 0.f, 0.f, 0.f};
  #pragma unroll
  for (int ks = 0; ks < 2; ++ks) {
    const bf16x8 ap = *(const bf16x8*)&ps[(wv * 16 + cl) * 72 + ks * 32 + cq * 8];
    #pragma unroll
    for (int nt = 0; nt < 2; ++nt) {
      const bf16x8 bv = *(const bf16x8*)&vT[(nt * 16 + cl) * 72 + ks * 32 + cq * 8];
      oacc[nt] = MFMA16(bv, ap, oacc[nt]);  // swapped: O^T fragment
    }
  }
  // lane holds O[wv*16 + cl][nt*16 + cq*4 + r]
  const long obase = (long)(b * 64 + wv * 16 + cl) * 512 + h * 32 + cq * 4;
  #pragma unroll
  for (int nt = 0; nt < 2; ++nt) {
    bf16x4 o;
    #pragma unroll
    for (int r = 0; r < 4; ++r) o[r] = (bf16)oacc[nt][r];
    *(bf16x4*)&out[obase + nt * 16] = o;
  }
}

extern "C" void kernel_launch(void* const* d_in, const int* in_sizes, int n_in,
                              void* d_out, int out_size, void* d_ws, size_t ws_size,
                              hipStream_t stream) {
  const float* x      = (const float*)d_in[0];
  const float* mask   = (const float*)d_in[1];
  const float* qkv_w  = (const float*)d_in[2];
  const float* q_bias = (const float*)d_in[3];
  const float* v_bias = (const float*)d_in[4];
  const float* lsc    = (const float*)d_in[5];
  const float* cpb_w1 = (const float*)d_in[6];
  const float* cpb_b1 = (const float*)d_in[7];
  const float* cpb_w2 = (const float*)d_in[8];
  const float* proj_w = (const float*)d_in[9];
  const float* proj_b = (const float*)d_in[10];
  const float* table  = (const float*)d_in[11];
  const int*   relidx = (const int*)d_in[12];

  char* ws = (char*)d_ws;
  bf16* qkvb   = (bf16*)(ws + OFF_QKV);
  bf16* xb     = (bf16*)(ws + OFF_XB);   // x_bf16, then reused as attn_out
  bf16* wqkv   = (bf16*)(ws + OFF_WQKV);
  bf16* wproj  = (bf16*)(ws + OFF_WPROJ);
  float* btab  = (float*)(ws + OFF_BT);
  float* rbias = (float*)(ws + OFF_RB);

  cvt_f32_bf16<<<16384, 256, 0, stream>>>(x, xb, 65536 * 512 / 8);
  cvt_f32_bf16<<<384, 256, 0, stream>>>(qkv_w, wqkv, 1536 * 512 / 8);
  cvt_f32_bf16<<<128, 256, 0, stream>>>(proj_w, wproj, 512 * 512 / 8);
  cpb_mlp<<<225, 256, 0, stream>>>(table, cpb_w1, cpb_b1, cpb_w2, btab);
  cpb_gather<<<256, 256, 0, stream>>>(btab, relidx, rbias);

  // QKV = x_bf16 @ qkv_w^T + [q_bias|0|v_bias]  -> bf16 [65536][1536]
  gemm_bt<1536, true><<<1536, 512, 0, stream>>>(xb, wqkv, (void*)qkvb, q_bias, v_bias);
  // fused cosine attention + bias + mask + softmax + PV -> bf16 [65536][512] (reuses xb)
  attn_kernel<<<16384, 256, 0, stream>>>(qkvb, mask, lsc, rbias, xb);
  // out = attn_out @ proj_w^T + proj_b -> fp32
  gemm_bt<512, false><<<512, 512, 0, stream>>>(xb, wproj, d_out, proj_b, nullptr);
}